// Round 1
// baseline (727.521 us; speedup 1.0000x reference)
//
#include <hip/hip_runtime.h>

#define BATCH 16384
#define KDIM  3072
#define NDIM  3072

typedef __bf16 bf16;
typedef bf16  bf16x8 __attribute__((ext_vector_type(8)));
typedef float f32x4  __attribute__((ext_vector_type(4)));

// async global->LDS, 16B per lane. HW dest = wave-uniform base + lane*16,
// which our lds addressing (tid*16) satisfies.
__device__ __forceinline__ void g2l16(const bf16* g, bf16* l) {
    __builtin_amdgcn_global_load_lds(
        (__attribute__((address_space(1))) unsigned int*)g,
        (__attribute__((address_space(3))) unsigned int*)l,
        16, 0, 0);
}

// ---- prep 1: fp32 inputs -> bf16, 8 elems/thread ----
__global__ __launch_bounds__(256) void cvt_a_kernel(const float* __restrict__ in,
                                                    bf16* __restrict__ out) {
    const long idx = (long)blockIdx.x * 256 + threadIdx.x;
    const float4* in4 = (const float4*)in;
    float4 a = in4[idx * 2];
    float4 b = in4[idx * 2 + 1];
    bf16x8 o;
    o[0] = (bf16)a.x; o[1] = (bf16)a.y; o[2] = (bf16)a.z; o[3] = (bf16)a.w;
    o[4] = (bf16)b.x; o[5] = (bf16)b.y; o[6] = (bf16)b.z; o[7] = (bf16)b.w;
    ((bf16x8*)out)[idx] = o;
}

// ---- prep 2: Weff_t[u][i] = bf16(w[i][u] * mask[u][i]) via LDS transpose ----
__global__ __launch_bounds__(256) void weff_kernel(const float* __restrict__ w,
                                                   const int* __restrict__ mask,
                                                   bf16* __restrict__ wt) {
    __shared__ float tile[32][33];  // +1 pad: no bank conflicts on transpose read
    const int i0 = blockIdx.x * 32;
    const int u0 = blockIdx.y * 32;
    const int tx = threadIdx.x, ty = threadIdx.y;
#pragma unroll
    for (int r = 0; r < 4; r++)
        tile[ty + 8 * r][tx] = w[(long)(i0 + ty + 8 * r) * NDIM + u0 + tx];
    __syncthreads();
#pragma unroll
    for (int r = 0; r < 4; r++) {
        int u = u0 + ty + 8 * r;
        int i = i0 + tx;
        float v = tile[tx][ty + 8 * r] * (float)mask[(long)u * KDIM + i];
        wt[(long)u * KDIM + i] = (bf16)v;
    }
}

// ---- main GEMM: C[m][n] = A[m][k] * Bt[n][k] + bias[n] ----
// 128x128 tile, BK=32, 4 waves in 2x2, each wave 64x64 via 4x4 mfma 16x16x32.
__global__ __launch_bounds__(256) void gemm_kernel(const bf16* __restrict__ A,   // [BATCH][KDIM]
                                                   const bf16* __restrict__ Bt,  // [NDIM][KDIM]
                                                   const float* __restrict__ bias,
                                                   float* __restrict__ C) {      // [BATCH][NDIM]
    __shared__ __align__(16) bf16 lds[8192];  // A tile 128x32 @0, B tile 128x32 @4096

    const int tid  = threadIdx.x;
    const int lane = tid & 63;
    const int wv   = tid >> 6;
    const long m0 = (long)blockIdx.y * 128;
    const long n0 = (long)blockIdx.x * 128;
    const int waveM = (wv >> 1) * 64;
    const int waveN = (wv & 1) * 64;

    // staging: linear chunk id = tid (+256), row = id>>2, 8-elem chunk = id&3
    const bf16* gA = A + (m0 + (tid >> 2)) * KDIM + (tid & 3) * 8;
    const bf16* gB = Bt + (n0 + (tid >> 2)) * KDIM + (tid & 3) * 8;
    bf16* lA = &lds[tid * 8];
    bf16* lB = &lds[4096 + tid * 8];

    // fragment read addresses (A: [m][k] k-contig, B: [n][k] k-contig)
    const int kq = (lane >> 4) * 8;
    const bf16* fA = &lds[(waveM + (lane & 15)) * 32 + kq];
    const bf16* fB = &lds[4096 + (waveN + (lane & 15)) * 32 + kq];

    f32x4 acc[4][4] = {};

    for (int k0 = 0; k0 < KDIM; k0 += 32) {
        __syncthreads();  // LDS consumed by previous iter's MFMAs
        g2l16(gA, lA);
        g2l16(gA + 64 * KDIM, lA + 2048);
        g2l16(gB, lB);
        g2l16(gB + 64 * KDIM, lB + 2048);
        gA += 32;
        gB += 32;
        __syncthreads();  // staging complete (compiler drains vmcnt)

        bf16x8 af[4], bfr[4];
#pragma unroll
        for (int i = 0; i < 4; i++) af[i] = *(const bf16x8*)(fA + i * 512);
#pragma unroll
        for (int i = 0; i < 4; i++) bfr[i] = *(const bf16x8*)(fB + i * 512);
#pragma unroll
        for (int mi = 0; mi < 4; mi++)
#pragma unroll
            for (int ni = 0; ni < 4; ni++)
                acc[mi][ni] = __builtin_amdgcn_mfma_f32_16x16x32_bf16(
                    af[mi], bfr[ni], acc[mi][ni], 0, 0, 0);
    }

    // epilogue: C/D layout col=lane&15, row=(lane>>4)*4+reg
#pragma unroll
    for (int mi = 0; mi < 4; mi++) {
#pragma unroll
        for (int ni = 0; ni < 4; ni++) {
            const long r = m0 + waveM + mi * 16 + (lane >> 4) * 4;
            const long c = n0 + waveN + ni * 16 + (lane & 15);
            const float bv = bias[c];
#pragma unroll
            for (int reg = 0; reg < 4; reg++)
                C[(r + reg) * NDIM + c] = acc[mi][ni][reg] + bv;
        }
    }
}

// ---- fallback (only if ws_size too small): naive fp32 masked GEMM ----
__global__ __launch_bounds__(256) void naive_kernel(const float* __restrict__ x,
                                                    const float* __restrict__ w,
                                                    const float* __restrict__ bias,
                                                    const int* __restrict__ mask,
                                                    float* __restrict__ out) {
    const long idx = (long)blockIdx.x * 256 + threadIdx.x;
    const long bi = idx / NDIM;
    const int u = (int)(idx % NDIM);
    float s = 0.f;
    for (int k = 0; k < KDIM; k++)
        s += x[bi * KDIM + k] * w[(long)k * NDIM + u] * (float)mask[(long)u * KDIM + k];
    out[idx] = s + bias[u];
}

extern "C" void kernel_launch(void* const* d_in, const int* in_sizes, int n_in,
                              void* d_out, int out_size, void* d_ws, size_t ws_size,
                              hipStream_t stream) {
    const float* x    = (const float*)d_in[0];  // [16384, 3072] fp32
    const float* w    = (const float*)d_in[1];  // [3072, 3072] fp32
    const float* bias = (const float*)d_in[2];  // [3072] fp32
    const int*   mask = (const int*)d_in[3];    // [3072, 3072] int32
    float* out = (float*)d_out;                 // [16384, 3072] fp32

    const size_t needA = (size_t)BATCH * KDIM * sizeof(bf16);  // ~100.7 MB
    const size_t needW = (size_t)NDIM * KDIM * sizeof(bf16);   // ~18.9 MB

    if (ws_size < needA + needW) {
        const long total = (long)BATCH * NDIM;
        naive_kernel<<<(int)(total / 256), 256, 0, stream>>>(x, w, bias, mask, out);
        return;
    }

    bf16* Abf = (bf16*)d_ws;
    bf16* Wt  = (bf16*)((char*)d_ws + needA);

    cvt_a_kernel<<<(BATCH * (KDIM / 8)) / 256, 256, 0, stream>>>(x, Abf);
    weff_kernel<<<dim3(KDIM / 32, NDIM / 32), dim3(32, 8), 0, stream>>>(w, mask, Wt);
    gemm_kernel<<<dim3(NDIM / 128, BATCH / 128), 256, 0, stream>>>(Abf, Wt, bias, out);
}